// Round 3
// baseline (112.297 us; speedup 1.0000x reference)
//
#include <hip/hip_runtime.h>
#include <hip/hip_bf16.h>
#include <stdint.h>

#define M_DIM 32
#define K_DIM 8192
#define N_DIM 8192
#define NGROUPS 64
#define GSZ 128
#define KSPLIT 4
#define KPART (K_DIM / KSPLIT)     // 2048
#define GPART (NGROUPS / KSPLIT)   // 16
#define BN 64

typedef __attribute__((ext_vector_type(8))) short short8;   // 8 bf16 (4 VGPRs)
typedef __attribute__((ext_vector_type(4))) float floatx4;  // MFMA acc

// ---------------------------------------------------------------------------
// Pre-kernel: A (fp32, 32x8192) -> Abf (bf16, octet-permuted [0,4,1,5,2,6,3,7])
// and R[m][g] = sum over group g of bf16-ROUNDED A (so the +128 offset in the
// fused dequant cancels EXACTLY against 136*R).  Also zeroes d_out (the
// harness poisons it to 0xAA before every launch), saving a memset dispatch.
// grid (32, 4) x 256 threads; each thread handles one octet of 8 k-values.
// ---------------------------------------------------------------------------
__global__ void marlin_prep_kernel(const float* __restrict__ A,
                                   uint16_t* __restrict__ Abf,
                                   float* __restrict__ R,
                                   float4* __restrict__ out4) {
    const int m = blockIdx.x;
    const int qtr = blockIdx.y;
    const int t = threadIdx.x;
    const int octet = qtr * 256 + t;     // 0..1023
    const int k0 = octet * 8;

    // zero 8 floats of out per thread: 32768 threads * 8 = 262144 = M*N
    {
        const int gtid = (qtr * 32 + m) * 256 + t;   // 0..32767
        const float4 z = make_float4(0.f, 0.f, 0.f, 0.f);
        out4[gtid * 2] = z;
        out4[gtid * 2 + 1] = z;
    }

    const float* a = A + m * K_DIM + k0;
    uint16_t b[8];
    float sum = 0.f;
#pragma unroll
    for (int j = 0; j < 8; j++) {
        union { __hip_bfloat16 h; uint16_t u; } cv;
        cv.h = __float2bfloat16(a[j]);   // round-to-nearest bf16
        b[j] = cv.u;
        sum += __bfloat162float(cv.h);   // sum of the ROUNDED values
    }
    // pack in permuted k-order [0,4,1,5,2,6,3,7] to match nibble-pair extract
    uint32_t w0 = (uint32_t)b[0] | ((uint32_t)b[4] << 16);
    uint32_t w1 = (uint32_t)b[1] | ((uint32_t)b[5] << 16);
    uint32_t w2 = (uint32_t)b[2] | ((uint32_t)b[6] << 16);
    uint32_t w3 = (uint32_t)b[3] | ((uint32_t)b[7] << 16);
    uint4 packed = make_uint4(w0, w1, w2, w3);
    *(uint4*)(Abf + (size_t)m * K_DIM + k0) = packed;

    // group = octet/16; threads t..t+15 share a group -> shfl reduce width 16
#pragma unroll
    for (int off = 1; off < 16; off <<= 1) sum += __shfl_xor(sum, off, 16);
    if ((t & 15) == 0) R[m * NGROUPS + qtr * 16 + (t >> 4)] = sum;
}

// ---------------------------------------------------------------------------
// Main kernel: grid (N/64, KSPLIT=4) x 512 threads (8 waves) = 512 blocks
// -> 2 blocks/CU, 4 waves/SIMD.  NO barriers in the K-loop: each lane's MFMA
// A-fragment is 16 contiguous bytes of the permuted Abf (L2-resident, 512 KB)
// loaded straight from global.  Per group: acc = sum A*(128+q) via MFMA, then
// C += s * (acc - 136*R).  Epilogue: fp32 atomicAdd into zeroed d_out.
// ---------------------------------------------------------------------------
__global__ __launch_bounds__(512, 4) void
MarlinQuantLinear_68556267979256_kernel(const int* __restrict__ qw,
                                        const float* __restrict__ scales,
                                        const float* __restrict__ bias,
                                        const uint16_t* __restrict__ Abf,
                                        const float* __restrict__ R,
                                        float* __restrict__ out) {
    __shared__ float r_lds[32 * 17];   // this quarter's 136*rowsums, pad 17

    const int bx = blockIdx.x;           // n-tile block
    const int bz = blockIdx.y;           // k-split quarter
    const int nbase = bx * BN;
    const int kbase = bz * KPART;
    const int gbase = bz * GPART;

    const int tid = threadIdx.x;
    const int w = tid >> 6;
    const int lane = tid & 63;
    const int quad = lane >> 4;
    const int l16 = lane & 15;
    const int mtile = w & 1;
    const int ntile = w >> 1;
    const int ncol = nbase + ntile * 16 + l16;

    // one-time stage of this quarter's R (prescaled by 136): 32m x 16g = 512
    {
        const int mm = tid >> 4, gg = tid & 15;
        r_lds[mm * 17 + gg] = 136.0f * R[mm * NGROUPS + gbase + gg];
    }
    __syncthreads();

    // per-lane A row pointer (permuted bf16 layout; fragment = 16 aligned B)
    const uint16_t* arow = Abf + (size_t)(mtile * 16 + l16) * K_DIM
                               + kbase + quad * 8;
    // per-lane qweight column pointer, at this quarter's first packed row
    const int* qcol = qw + (size_t)(kbase >> 3) * N_DIM + ncol;
    const float* scol = scales + (size_t)gbase * N_DIM + ncol;

    floatx4 C = {0.f, 0.f, 0.f, 0.f};

#pragma unroll 2
    for (int g = 0; g < GPART; g++) {
        const float s = scol[g * N_DIM];
        floatx4 accg = {0.f, 0.f, 0.f, 0.f};
#pragma unroll
        for (int t = 0; t < 4; t++) {
            // one int32 = exactly this lane's 8-nibble B fragment
            const uint32_t q = (uint32_t)qcol[(g * 16 + t * 4 + quad) * N_DIM];
            union { uint32_t u[4]; short8 v; } fb;
            fb.u[0] = ( q        & 0x000F000Fu) | 0x43004300u;  // k0,k4
            fb.u[1] = ((q >> 4)  & 0x000F000Fu) | 0x43004300u;  // k1,k5
            fb.u[2] = ((q >> 8)  & 0x000F000Fu) | 0x43004300u;  // k2,k6
            fb.u[3] = ((q >> 12) & 0x000F000Fu) | 0x43004300u;  // k3,k7
            const short8 fa = *(const short8*)(arow + g * 128 + t * 32);
            accg = __builtin_amdgcn_mfma_f32_16x16x32_bf16(fa, fb.v, accg, 0, 0, 0);
        }
#pragma unroll
        for (int r = 0; r < 4; r++) {
            // acc row is global m = mtile*16 + quad*4 + r; r_lds holds 136*R
            const float tval = accg[r] - r_lds[(mtile * 16 + quad * 4 + r) * 17 + g];
            C[r] = fmaf(s, tval, C[r]);
        }
    }

    const float bv = (bz == 0) ? bias[ncol] : 0.0f;
#pragma unroll
    for (int r = 0; r < 4; r++) {
        const int m = mtile * 16 + quad * 4 + r;   // C/D row = quad*4 + reg
        atomicAdd(&out[(size_t)m * N_DIM + ncol], C[r] + bv);
    }
}

extern "C" void kernel_launch(void* const* d_in, const int* in_sizes, int n_in,
                              void* d_out, int out_size, void* d_ws, size_t ws_size,
                              hipStream_t stream) {
    const float* A      = (const float*)d_in[0];
    const int*   qw     = (const int*)d_in[1];
    const float* scales = (const float*)d_in[2];
    const float* bias   = (const float*)d_in[3];
    float* out = (float*)d_out;

    uint16_t* Abf = (uint16_t*)d_ws;                                   // 512 KB
    float*    R   = (float*)((char*)d_ws + (size_t)M_DIM * K_DIM * 2); //   8 KB

    marlin_prep_kernel<<<dim3(M_DIM, 4), 256, 0, stream>>>(A, Abf, R, (float4*)out);
    MarlinQuantLinear_68556267979256_kernel<<<dim3(N_DIM / BN, KSPLIT), 512, 0, stream>>>(
        qw, scales, bias, Abf, R, out);
}

// Round 4
// 109.686 us; speedup vs baseline: 1.0238x; 1.0238x over previous
//
#include <hip/hip_runtime.h>
#include <hip/hip_bf16.h>
#include <stdint.h>

#define M_DIM 32
#define K_DIM 8192
#define N_DIM 8192
#define NGROUPS 64
#define GSZ 128
#define KSPLIT 8
#define KPART (K_DIM / KSPLIT)     // 1024
#define GPART (NGROUPS / KSPLIT)   // 8
#define BN 64

typedef __attribute__((ext_vector_type(8))) short short8;   // 8 bf16 (4 VGPRs)
typedef __attribute__((ext_vector_type(4))) float floatx4;  // MFMA acc

// ---------------------------------------------------------------------------
// Pre-kernel: A (fp32, 32x8192) -> Abf (bf16, octet-permuted [0,4,1,5,2,6,3,7])
// and R[m][g] = sum over group g of bf16-ROUNDED A (so the +128 offset in the
// fused dequant cancels EXACTLY against 136*R).  Also zeroes d_out (the
// harness poisons it to 0xAA before every launch), saving a memset dispatch.
// grid (32, 4) x 256 threads; each thread handles one octet of 8 k-values.
// ---------------------------------------------------------------------------
__global__ void marlin_prep_kernel(const float* __restrict__ A,
                                   uint16_t* __restrict__ Abf,
                                   float* __restrict__ R,
                                   float4* __restrict__ out4) {
    const int m = blockIdx.x;
    const int qtr = blockIdx.y;
    const int t = threadIdx.x;
    const int octet = qtr * 256 + t;     // 0..1023
    const int k0 = octet * 8;

    // zero 8 floats of out per thread: 32768 threads * 8 = 262144 = M*N
    {
        const int gtid = (qtr * 32 + m) * 256 + t;   // 0..32767
        const float4 z = make_float4(0.f, 0.f, 0.f, 0.f);
        out4[gtid * 2] = z;
        out4[gtid * 2 + 1] = z;
    }

    const float* a = A + m * K_DIM + k0;
    uint16_t b[8];
    float sum = 0.f;
#pragma unroll
    for (int j = 0; j < 8; j++) {
        union { __hip_bfloat16 h; uint16_t u; } cv;
        cv.h = __float2bfloat16(a[j]);   // round-to-nearest bf16
        b[j] = cv.u;
        sum += __bfloat162float(cv.h);   // sum of the ROUNDED values
    }
    // pack in permuted k-order [0,4,1,5,2,6,3,7] to match nibble-pair extract
    uint32_t w0 = (uint32_t)b[0] | ((uint32_t)b[4] << 16);
    uint32_t w1 = (uint32_t)b[1] | ((uint32_t)b[5] << 16);
    uint32_t w2 = (uint32_t)b[2] | ((uint32_t)b[6] << 16);
    uint32_t w3 = (uint32_t)b[3] | ((uint32_t)b[7] << 16);
    uint4 packed = make_uint4(w0, w1, w2, w3);
    *(uint4*)(Abf + (size_t)m * K_DIM + k0) = packed;

    // group = octet/16; threads t..t+15 share a group -> shfl reduce width 16
#pragma unroll
    for (int off = 1; off < 16; off <<= 1) sum += __shfl_xor(sum, off, 16);
    if ((t & 15) == 0) R[m * NGROUPS + qtr * 16 + (t >> 4)] = sum;
}

// ---------------------------------------------------------------------------
// Main kernel: grid (N/64, KSPLIT=8) x 512 threads (8 waves) = 1024 blocks.
// R3 post-mortem: latency-bound (MfmaUtil 3%, VALUBusy 13%, HBM 6%) — the
// in-loop q loads drained a ~700cyc L3 round-trip every 2 groups.  R4: each
// lane PREFETCHES its entire q working set (8 groups x 4 dwords = 32 VGPR)
// and all 8 scales up front -> ONE initial stall, then the fully-unrolled
// K-loop streams from registers, with A fragments register-pipelined one
// group ahead from L1/L2-resident Abf.  No barriers in the loop.
// Epilogue: fp32 atomicAdd into zeroed d_out (bx fastest in grid ->
// same-bx partials land on one XCD -> atomics stay L2-local).
// ---------------------------------------------------------------------------
__global__ __launch_bounds__(512, 4) void
MarlinQuantLinear_68556267979256_kernel(const int* __restrict__ qw,
                                        const float* __restrict__ scales,
                                        const float* __restrict__ bias,
                                        const uint16_t* __restrict__ Abf,
                                        const float* __restrict__ R,
                                        float* __restrict__ out) {
    __shared__ float r_lds[32 * 9];   // this part's 136*rowsums, pad stride 9

    const int bx = blockIdx.x;           // n-tile block (fastest)
    const int bz = blockIdx.y;           // k-split part
    const int nbase = bx * BN;
    const int kbase = bz * KPART;
    const int gbase = bz * GPART;

    const int tid = threadIdx.x;
    const int w = tid >> 6;
    const int lane = tid & 63;
    const int quad = lane >> 4;
    const int l16 = lane & 15;
    const int mtile = w & 1;
    const int ntile = w >> 1;
    const int ncol = nbase + ntile * 16 + l16;

    // one-time stage of this part's R (prescaled by 136): 32m x 8g = 256
    if (tid < 256) {
        const int mm = tid >> 3, gg = tid & 7;
        r_lds[mm * 9 + gg] = 136.0f * R[mm * NGROUPS + gbase + gg];
    }
    __syncthreads();

    // ---- full prefetch: scales (8) and qweight (32 dwords) ----
    const float* scol = scales + (size_t)gbase * N_DIM + ncol;
    float s[GPART];
#pragma unroll
    for (int g = 0; g < GPART; g++) s[g] = scol[g * N_DIM];

    const int* qcol = qw + (size_t)(kbase >> 3) * N_DIM + ncol;
    uint32_t qv[GPART][4];
#pragma unroll
    for (int g = 0; g < GPART; g++)
#pragma unroll
        for (int t = 0; t < 4; t++)
            qv[g][t] = (uint32_t)qcol[(g * 16 + t * 4 + quad) * N_DIM];

    // ---- A fragment pipeline (global, L1/L2-resident; 16B aligned) ----
    const uint16_t* arow = Abf + (size_t)(mtile * 16 + l16) * K_DIM
                               + kbase + quad * 8;
    short8 a_cur[4];
#pragma unroll
    for (int t = 0; t < 4; t++)
        a_cur[t] = *(const short8*)(arow + t * 32);

    floatx4 C = {0.f, 0.f, 0.f, 0.f};

#pragma unroll
    for (int g = 0; g < GPART; g++) {
        short8 a_nxt[4];
        if (g + 1 < GPART) {
#pragma unroll
            for (int t = 0; t < 4; t++)
                a_nxt[t] = *(const short8*)(arow + (g + 1) * 128 + t * 32);
        }
        floatx4 accg = {0.f, 0.f, 0.f, 0.f};
#pragma unroll
        for (int t = 0; t < 4; t++) {
            const uint32_t q = qv[g][t];
            union { uint32_t u[4]; short8 v; } fb;
            fb.u[0] = ( q        & 0x000F000Fu) | 0x43004300u;  // k0,k4
            fb.u[1] = ((q >> 4)  & 0x000F000Fu) | 0x43004300u;  // k1,k5
            fb.u[2] = ((q >> 8)  & 0x000F000Fu) | 0x43004300u;  // k2,k6
            fb.u[3] = ((q >> 12) & 0x000F000Fu) | 0x43004300u;  // k3,k7
            accg = __builtin_amdgcn_mfma_f32_16x16x32_bf16(a_cur[t], fb.v, accg, 0, 0, 0);
        }
#pragma unroll
        for (int r = 0; r < 4; r++) {
            // acc row is global m = mtile*16 + quad*4 + r; r_lds holds 136*R
            const float tval = accg[r] - r_lds[(mtile * 16 + quad * 4 + r) * 9 + g];
            C[r] = fmaf(s[g], tval, C[r]);
        }
        if (g + 1 < GPART) {
#pragma unroll
            for (int t = 0; t < 4; t++) a_cur[t] = a_nxt[t];
        }
    }

    const float bv = (bz == 0) ? bias[ncol] : 0.0f;
#pragma unroll
    for (int r = 0; r < 4; r++) {
        const int m = mtile * 16 + quad * 4 + r;   // C/D row = quad*4 + reg
        atomicAdd(&out[(size_t)m * N_DIM + ncol], C[r] + bv);
    }
}

extern "C" void kernel_launch(void* const* d_in, const int* in_sizes, int n_in,
                              void* d_out, int out_size, void* d_ws, size_t ws_size,
                              hipStream_t stream) {
    const float* A      = (const float*)d_in[0];
    const int*   qw     = (const int*)d_in[1];
    const float* scales = (const float*)d_in[2];
    const float* bias   = (const float*)d_in[3];
    float* out = (float*)d_out;

    uint16_t* Abf = (uint16_t*)d_ws;                                   // 512 KB
    float*    R   = (float*)((char*)d_ws + (size_t)M_DIM * K_DIM * 2); //   8 KB

    marlin_prep_kernel<<<dim3(M_DIM, 4), 256, 0, stream>>>(A, Abf, R, (float4*)out);
    MarlinQuantLinear_68556267979256_kernel<<<dim3(N_DIM / BN, KSPLIT), 512, 0, stream>>>(
        qw, scales, bias, Abf, R, out);
}

// Round 5
// 91.214 us; speedup vs baseline: 1.2311x; 1.2025x over previous
//
#include <hip/hip_runtime.h>
#include <hip/hip_bf16.h>
#include <stdint.h>

#define M_DIM 32
#define K_DIM 8192
#define N_DIM 8192
#define NGROUPS 64
#define KSPLIT 8
#define KPART (K_DIM / KSPLIT)     // 1024
#define GPART (NGROUPS / KSPLIT)   // 8
#define BN 64

#define QSTRIDE 72   // dwords per q-row in LDS: 64+8 -> exact 2-way (free)
#define ASTRIDE 66   // dwords per A-row in LDS: 64+2 -> balanced ds_read_b128

typedef __attribute__((ext_vector_type(8))) short short8;   // 8 bf16 (4 VGPRs)
typedef __attribute__((ext_vector_type(4))) float floatx4;  // MFMA acc

// ---------------------------------------------------------------------------
// Pre-kernel: A (fp32, 32x8192) -> Abf (bf16, octet-permuted [0,4,1,5,2,6,3,7])
// and R[m][g] = sum over group g of bf16-ROUNDED A (so the +128 offset in the
// fused dequant cancels EXACTLY against 136*R).  Also zeroes d_out.
// ---------------------------------------------------------------------------
__global__ void marlin_prep_kernel(const float* __restrict__ A,
                                   uint16_t* __restrict__ Abf,
                                   float* __restrict__ R,
                                   float4* __restrict__ out4) {
    const int m = blockIdx.x;
    const int qtr = blockIdx.y;
    const int t = threadIdx.x;
    const int octet = qtr * 256 + t;     // 0..1023
    const int k0 = octet * 8;

    {   // zero out: 32768 threads * 8 floats = 262144 = M*N
        const int gtid = (qtr * 32 + m) * 256 + t;
        const float4 z = make_float4(0.f, 0.f, 0.f, 0.f);
        out4[gtid * 2] = z;
        out4[gtid * 2 + 1] = z;
    }

    const float* a = A + m * K_DIM + k0;
    uint16_t b[8];
    float sum = 0.f;
#pragma unroll
    for (int j = 0; j < 8; j++) {
        union { __hip_bfloat16 h; uint16_t u; } cv;
        cv.h = __float2bfloat16(a[j]);   // round-to-nearest bf16
        b[j] = cv.u;
        sum += __bfloat162float(cv.h);   // sum of the ROUNDED values
    }
    // pack in permuted k-order [0,4,1,5,2,6,3,7] to match nibble-pair extract
    uint32_t w0 = (uint32_t)b[0] | ((uint32_t)b[4] << 16);
    uint32_t w1 = (uint32_t)b[1] | ((uint32_t)b[5] << 16);
    uint32_t w2 = (uint32_t)b[2] | ((uint32_t)b[6] << 16);
    uint32_t w3 = (uint32_t)b[3] | ((uint32_t)b[7] << 16);
    *(uint4*)(Abf + (size_t)m * K_DIM + k0) = make_uint4(w0, w1, w2, w3);

#pragma unroll
    for (int off = 1; off < 16; off <<= 1) sum += __shfl_xor(sum, off, 16);
    if ((t & 15) == 0) R[m * NGROUPS + qtr * 16 + (t >> 4)] = sum;
}

// ---------------------------------------------------------------------------
// Main kernel: grid (N/64, KSPLIT=8) x 512 threads (8 waves).
// R4 post-mortem: column-pattern global reads (32KB-stride q dwords, 16KB-
// stride A fragments) serialize the memory system at ~520 GB/s regardless of
// prefetch/barriers.  R5: stage q and A tiles through LDS with COALESCED
// row-contiguous global loads (Marlin-style), double-buffered, one barrier
// per group; fragments come from padded LDS (2-way bank aliasing = free).
// ---------------------------------------------------------------------------
__global__ __launch_bounds__(512, 4) void
MarlinQuantLinear_68556267979256_kernel(const int* __restrict__ qw,
                                        const float* __restrict__ scales,
                                        const float* __restrict__ bias,
                                        const uint16_t* __restrict__ Abf,
                                        const float* __restrict__ R,
                                        float* __restrict__ out) {
    __shared__ uint32_t qbuf[2][16 * QSTRIDE];   //  9216 B
    __shared__ uint32_t abuf[2][32 * ASTRIDE];   // 16896 B
    __shared__ float    r_lds[32 * 9];           //  1152 B

    const int bx = blockIdx.x;           // n-tile block (fastest)
    const int bz = blockIdx.y;           // k-split part
    const int nbase = bx * BN;
    const int gbase = bz * GPART;

    const int tid = threadIdx.x;
    const int w = tid >> 6;
    const int lane = tid & 63;
    const int quad = lane >> 4;
    const int l16 = lane & 15;
    const int mtile = w & 1;
    const int ntile = w >> 1;
    const int ncol = nbase + ntile * 16 + l16;

    // one-time stage of this part's R (prescaled by 136): 32m x 8g = 256
    if (tid < 256) {
        const int mm = tid >> 3, gg = tid & 7;
        r_lds[mm * 9 + gg] = 136.0f * R[mm * NGROUPS + gbase + gg];
    }

    // scale prefetch (8 strided instrs, in flight during first stage)
    const float* scol = scales + (size_t)gbase * N_DIM + ncol;
    float s[GPART];
#pragma unroll
    for (int g = 0; g < GPART; g++) s[g] = scol[g * N_DIM];

    // ---- coalesced staging maps ----
    // q: thread -> (row qr 0..15, col pair qc): lanes read 8 contiguous bytes
    const int qr = tid >> 5;
    const int qc = (tid & 31) * 2;
    const int* qsrc = qw + ((size_t)(bz * 128 + qr) * N_DIM) + nbase + qc;
    // A: thread -> (row am 0..31, 16B segment): lanes read 16 contiguous bytes
    const int am = tid >> 4;
    const int aseg = (tid & 15) * 4;                  // dword offset in row
    const uint32_t* Ad = (const uint32_t*)Abf;        // 4096 dwords per row
    const uint32_t* asrc = Ad + (size_t)am * (K_DIM / 2) + bz * (KPART / 2) + aseg;

    // initial tile (g=0)
    uint2 qst = *(const uint2*)(qsrc);
    uint4 ast = *(const uint4*)(asrc);

    floatx4 C = {0.f, 0.f, 0.f, 0.f};

#pragma unroll
    for (int g = 0; g < GPART; g++) {
        // issue next tile's global loads (drained at next barrier; compute +
        // multi-wave overlap hides most of the latency)
        uint2 qnx; uint4 anx;
        if (g + 1 < GPART) {
            qnx = *(const uint2*)(qsrc + (size_t)(g + 1) * 16 * N_DIM);
            anx = *(const uint4*)(asrc + (g + 1) * 64);
        }
        // stage current tile into this group's buffer
        *(uint2*)&qbuf[g & 1][qr * QSTRIDE + qc] = qst;
        *(uint4*)&abuf[g & 1][am * ASTRIDE + aseg] = ast;
        __syncthreads();

        floatx4 accg = {0.f, 0.f, 0.f, 0.f};
#pragma unroll
        for (int t = 0; t < 4; t++) {
            // lane's 8-nibble B fragment: one dword from padded LDS
            const uint32_t q = qbuf[g & 1][(t * 4 + quad) * QSTRIDE + ntile * 16 + l16];
            union { uint32_t u[4]; short8 v; } fb;
            fb.u[0] = ( q        & 0x000F000Fu) | 0x43004300u;  // k0,k4
            fb.u[1] = ((q >> 4)  & 0x000F000Fu) | 0x43004300u;  // k1,k5
            fb.u[2] = ((q >> 8)  & 0x000F000Fu) | 0x43004300u;  // k2,k6
            fb.u[3] = ((q >> 12) & 0x000F000Fu) | 0x43004300u;  // k3,k7
            const short8 fa =
                *(const short8*)&abuf[g & 1][(mtile * 16 + l16) * ASTRIDE + t * 16 + quad * 4];
            accg = __builtin_amdgcn_mfma_f32_16x16x32_bf16(fa, fb.v, accg, 0, 0, 0);
        }
#pragma unroll
        for (int r = 0; r < 4; r++) {
            // acc row is global m = mtile*16 + quad*4 + r; r_lds holds 136*R
            const float tval = accg[r] - r_lds[(mtile * 16 + quad * 4 + r) * 9 + g];
            C[r] = fmaf(s[g], tval, C[r]);
        }
        qst = qnx;
        ast = anx;
    }

    const float bv = (bz == 0) ? bias[ncol] : 0.0f;
#pragma unroll
    for (int r = 0; r < 4; r++) {
        const int m = mtile * 16 + quad * 4 + r;   // C/D row = quad*4 + reg
        atomicAdd(&out[(size_t)m * N_DIM + ncol], C[r] + bv);
    }
}

extern "C" void kernel_launch(void* const* d_in, const int* in_sizes, int n_in,
                              void* d_out, int out_size, void* d_ws, size_t ws_size,
                              hipStream_t stream) {
    const float* A      = (const float*)d_in[0];
    const int*   qw     = (const int*)d_in[1];
    const float* scales = (const float*)d_in[2];
    const float* bias   = (const float*)d_in[3];
    float* out = (float*)d_out;

    uint16_t* Abf = (uint16_t*)d_ws;                                   // 512 KB
    float*    R   = (float*)((char*)d_ws + (size_t)M_DIM * K_DIM * 2); //   8 KB

    marlin_prep_kernel<<<dim3(M_DIM, 4), 256, 0, stream>>>(A, Abf, R, (float4*)out);
    MarlinQuantLinear_68556267979256_kernel<<<dim3(N_DIM / BN, KSPLIT), 512, 0, stream>>>(
        qw, scales, bias, Abf, R, out);
}